// Round 1
// baseline (83.247 us; speedup 1.0000x reference)
//
#include <hip/hip_runtime.h>
#include <math.h>

#define H 1024
#define V 50257
#define L 512

// ws float offsets
#define WS_LOGITS  0        // 512 attn logits
#define WS_W       512      // 512 attn weights
#define WS_ATTN    1024     // 1024 attn_applied (atomic accum, zeroed by k2)
#define WS_X       2048     // 1024 combine output
#define WS_GATES   3072     // 4096 lstm gates
#define WS_H       7168     // 1024 new h
#define WS_C       8192     // 1024 new c
#define WS_SCAL    9216     // 2 scalars: max, log(sumexp)
#define WS_VLOG    9344     // 50257 vocab logits

__device__ __forceinline__ float wave_sum(float v) {
    for (int o = 32; o > 0; o >>= 1) v += __shfl_down(v, o, 64);
    return v;
}
__device__ __forceinline__ float sigf(float x) { return 1.0f / (1.0f + expf(-x)); }
__device__ __forceinline__ float dot4(float4 a, float4 b) {
    return a.x * b.x + a.y * b.y + a.z * b.z + a.w * b.w;
}

// K1: attn_logits[r] = dot(concat(embedded, h0), attn_W[r]) + attn_b[r]
// grid 512 blocks x 256 threads, one block per row
__global__ void k1_attn_logits(const int* __restrict__ tok,
                               const float* __restrict__ hidden,
                               const float* __restrict__ emb,
                               const float* __restrict__ attn_W,
                               const float* __restrict__ attn_b,
                               float* __restrict__ ws) {
    int r = blockIdx.x, t = threadIdx.x;
    size_t token = (size_t)tok[0];
    const float4* rw = (const float4*)(attn_W + (size_t)r * 2 * H); // 512 float4
    const float4* ev = (const float4*)(emb + token * H);            // 256 float4
    const float4* hv = (const float4*)hidden;                       // 256 float4
    float acc = dot4(ev[t], rw[t]) + dot4(hv[t], rw[256 + t]);
    float s = wave_sum(acc);
    __shared__ float red[4];
    if ((t & 63) == 0) red[t >> 6] = s;
    __syncthreads();
    if (t == 0) ws[WS_LOGITS + r] = red[0] + red[1] + red[2] + red[3] + attn_b[r];
}

// K2: softmax over 512 logits; also zero attn_applied accumulator.
// 1 block x 512 threads
__global__ void k2_softmax(float* __restrict__ ws, float* __restrict__ out) {
    int t = threadIdx.x;
    // zero accumulator for K3 (visible at kernel boundary)
    ws[WS_ATTN + t] = 0.0f;
    ws[WS_ATTN + 512 + t] = 0.0f;
    float v = ws[WS_LOGITS + t];
    float m = v;
    for (int o = 32; o > 0; o >>= 1) m = fmaxf(m, __shfl_down(m, o, 64));
    __shared__ float red[8];
    __shared__ float bm, bs;
    if ((t & 63) == 0) red[t >> 6] = m;
    __syncthreads();
    if (t == 0) {
        float mm = red[0];
        for (int i = 1; i < 8; ++i) mm = fmaxf(mm, red[i]);
        bm = mm;
    }
    __syncthreads();
    float e = expf(v - bm);
    float s = wave_sum(e);
    if ((t & 63) == 0) red[t >> 6] = s;
    __syncthreads();
    if (t == 0) {
        float ss = 0.f;
        for (int i = 0; i < 8; ++i) ss += red[i];
        bs = ss;
    }
    __syncthreads();
    float w = e / bs;
    ws[WS_W + t] = w;
    out[V + 2 * H + t] = w;  // attn_weights output
}

// K3: attn_applied[j] = sum_l w[l]*enc[l][j].
// grid 128 blocks (4 j-splits x 32 l-chunks of 16) x 256 threads, atomicAdd.
__global__ void k3_attn_applied(const float* __restrict__ enc, float* __restrict__ ws) {
    int t = threadIdx.x;
    int jb = blockIdx.x >> 5;   // 0..3
    int lc = blockIdx.x & 31;   // 0..31
    int j = jb * 256 + t;
    float acc = 0.f;
    int l0 = lc * 16;
#pragma unroll
    for (int i = 0; i < 16; ++i) {
        int l = l0 + i;
        acc += ws[WS_W + l] * enc[(size_t)l * H + j];
    }
    atomicAdd(&ws[WS_ATTN + j], acc);
}

// K4: x[i] = relu(dot(concat(embedded, attn_applied), comb_W[i]) + comb_b[i])
// grid 64 blocks x 256 threads (4 waves x 4 rows each = 16 rows/block)
__global__ void k4_combine(const int* __restrict__ tok,
                           const float* __restrict__ emb,
                           const float* __restrict__ comb_W,
                           const float* __restrict__ comb_b,
                           float* __restrict__ ws) {
    int t = threadIdx.x;
    int w = t >> 6, l = t & 63;
    size_t token = (size_t)tok[0];
    __shared__ float4 vec4[512]; // embedded (256) ++ attn (256)
    vec4[t] = ((const float4*)(emb + token * H))[t];
    vec4[256 + t] = ((const float4*)(ws + WS_ATTN))[t];
    __syncthreads();
    const float4* cw = (const float4*)comb_W;
#pragma unroll
    for (int rr = 0; rr < 4; ++rr) {
        int r = blockIdx.x * 16 + w * 4 + rr;
        float acc = 0.f;
#pragma unroll
        for (int i = 0; i < 8; ++i)
            acc += dot4(cw[(size_t)r * 512 + i * 64 + l], vec4[i * 64 + l]);
        float s = wave_sum(acc);
        if (l == 0) ws[WS_X + r] = fmaxf(s + comb_b[r], 0.0f);
    }
}

// K5: gates[k] = dot(x, W_ih[k]) + dot(h0, W_hh[k]) + b_ih[k] + b_hh[k]
// grid 256 blocks x 256 threads (16 rows/block)
__global__ void k5_gates(const float* __restrict__ hidden,
                         const float* __restrict__ W_ih,
                         const float* __restrict__ W_hh,
                         const float* __restrict__ b_ih,
                         const float* __restrict__ b_hh,
                         float* __restrict__ ws) {
    int t = threadIdx.x;
    int w = t >> 6, l = t & 63;
    __shared__ float4 xs[256], hs[256];
    xs[t] = ((const float4*)(ws + WS_X))[t];
    hs[t] = ((const float4*)hidden)[t];
    __syncthreads();
    const float4* wi = (const float4*)W_ih;
    const float4* wh = (const float4*)W_hh;
#pragma unroll
    for (int rr = 0; rr < 4; ++rr) {
        int k = blockIdx.x * 16 + w * 4 + rr;
        float acc = 0.f;
#pragma unroll
        for (int i = 0; i < 4; ++i) {
            acc += dot4(wi[(size_t)k * 256 + i * 64 + l], xs[i * 64 + l]);
            acc += dot4(wh[(size_t)k * 256 + i * 64 + l], hs[i * 64 + l]);
        }
        float s = wave_sum(acc);
        if (l == 0) ws[WS_GATES + k] = s + b_ih[k] + b_hh[k];
    }
}

// K6: LSTM pointwise. grid 4 x 256.
__global__ void k6_lstm(const float* __restrict__ hidden,
                        float* __restrict__ ws, float* __restrict__ out) {
    int n = blockIdx.x * 256 + threadIdx.x;
    float ig = ws[WS_GATES + n];
    float fg = ws[WS_GATES + H + n];
    float gg = ws[WS_GATES + 2 * H + n];
    float og = ws[WS_GATES + 3 * H + n];
    float c0 = hidden[n];
    float c = sigf(fg) * c0 + sigf(ig) * tanhf(gg);
    float h = sigf(og) * tanhf(c);
    ws[WS_H + n] = h;
    ws[WS_C + n] = c;
    out[V + n] = h;
    out[V + H + n] = c;
}

// K7: vocab logits[r] = dot(h, out_W[r]) + out_b[r]
// grid 1571 blocks x 256 threads; 4 waves x 8 rows = 32 rows/block
__global__ void k7_vocab(const float* __restrict__ out_W,
                         const float* __restrict__ out_b,
                         float* __restrict__ ws) {
    int t = threadIdx.x;
    int w = t >> 6, l = t & 63;
    const float4* h4 = (const float4*)(ws + WS_H);
    float4 hr[4];
#pragma unroll
    for (int i = 0; i < 4; ++i) hr[i] = h4[i * 64 + l];
    const float4* ow = (const float4*)out_W;
#pragma unroll
    for (int rr = 0; rr < 8; ++rr) {
        int r = blockIdx.x * 32 + w * 8 + rr;
        if (r >= V) break;
        float acc = 0.f;
#pragma unroll
        for (int i = 0; i < 4; ++i)
            acc += dot4(ow[(size_t)r * 256 + i * 64 + l], hr[i]);
        float s = wave_sum(acc);
        if (l == 0) ws[WS_VLOG + r] = s + out_b[r];
    }
}

// K8: max + log-sum-exp over V logits. 1 block x 1024 threads.
__global__ void k8_lse(float* __restrict__ ws) {
    int t = threadIdx.x;
    float m = -INFINITY;
    for (int r = t; r < V; r += 1024) m = fmaxf(m, ws[WS_VLOG + r]);
    for (int o = 32; o > 0; o >>= 1) m = fmaxf(m, __shfl_down(m, o, 64));
    __shared__ float red[16];
    __shared__ float bm, bs;
    if ((t & 63) == 0) red[t >> 6] = m;
    __syncthreads();
    if (t == 0) {
        float mm = red[0];
        for (int i = 1; i < 16; ++i) mm = fmaxf(mm, red[i]);
        bm = mm;
    }
    __syncthreads();
    float mv = bm;
    float s = 0.f;
    for (int r = t; r < V; r += 1024) s += expf(ws[WS_VLOG + r] - mv);
    s = wave_sum(s);
    if ((t & 63) == 0) red[t >> 6] = s;
    __syncthreads();
    if (t == 0) {
        float ss = 0.f;
        for (int i = 0; i < 16; ++i) ss += red[i];
        bs = ss;
        ws[WS_SCAL] = mv;
        ws[WS_SCAL + 1] = logf(bs);
    }
}

// K9: out[r] = logit[r] - m - lse. grid 197 x 256.
__global__ void k9_write(const float* __restrict__ ws, float* __restrict__ out) {
    int r = blockIdx.x * 256 + threadIdx.x;
    if (r < V) out[r] = ws[WS_VLOG + r] - ws[WS_SCAL] - ws[WS_SCAL + 1];
}

extern "C" void kernel_launch(void* const* d_in, const int* in_sizes, int n_in,
                              void* d_out, int out_size, void* d_ws, size_t ws_size,
                              hipStream_t stream) {
    const int*   tok     = (const int*)d_in[0];
    const float* hidden  = (const float*)d_in[1];
    const float* enc     = (const float*)d_in[2];
    const float* emb     = (const float*)d_in[3];
    const float* attn_W  = (const float*)d_in[4];
    const float* attn_b  = (const float*)d_in[5];
    const float* comb_W  = (const float*)d_in[6];
    const float* comb_b  = (const float*)d_in[7];
    const float* W_ih    = (const float*)d_in[8];
    const float* W_hh    = (const float*)d_in[9];
    const float* b_ih    = (const float*)d_in[10];
    const float* b_hh    = (const float*)d_in[11];
    const float* out_W   = (const float*)d_in[12];
    const float* out_b   = (const float*)d_in[13];
    float* out = (float*)d_out;
    float* ws  = (float*)d_ws;

    k1_attn_logits<<<512, 256, 0, stream>>>(tok, hidden, emb, attn_W, attn_b, ws);
    k2_softmax<<<1, 512, 0, stream>>>(ws, out);
    k3_attn_applied<<<128, 256, 0, stream>>>(enc, ws);
    k4_combine<<<64, 256, 0, stream>>>(tok, emb, comb_W, comb_b, ws);
    k5_gates<<<256, 256, 0, stream>>>(hidden, W_ih, W_hh, b_ih, b_hh, ws);
    k6_lstm<<<4, 256, 0, stream>>>(hidden, ws, out);
    k7_vocab<<<1571, 256, 0, stream>>>(out_W, out_b, ws);
    k8_lse<<<1, 1024, 0, stream>>>(ws);
    k9_write<<<197, 256, 0, stream>>>(ws, out);
}

// Round 2
// 63.782 us; speedup vs baseline: 1.3052x; 1.3052x over previous
//
#include <hip/hip_runtime.h>
#include <math.h>

#define H 1024
#define V 50257
#define L 512
#define NPART 1571   // ceil(V/32) vocab blocks

// ws float offsets
#define WS_LOGITS 0                 // 512 attn logits
#define WS_ATTN   512               // 1024 attn_applied (atomic accum, zeroed by kA)
#define WS_X      1536              // 1024 combine output
#define WS_H      2560              // 1024 new h
#define WS_VLOG   3584              // 50257 vocab logits
#define WS_PART   53844             // NPART*2 online-softmax partials (m,s)

__device__ __forceinline__ float wave_sum(float v) {
    for (int o = 32; o > 0; o >>= 1) v += __shfl_down(v, o, 64);
    return v;
}
__device__ __forceinline__ float sigf(float x) { return 1.0f / (1.0f + expf(-x)); }
__device__ __forceinline__ float dot4(float4 a, float4 b) {
    return a.x * b.x + a.y * b.y + a.z * b.z + a.w * b.w;
}
// online-softmax merge: (m,s) <- (m,s) ⊕ (m2,s2)
__device__ __forceinline__ void osm_merge(float& m, float& s, float m2, float s2) {
    float M = fmaxf(m, m2);
    if (M == -INFINITY) { m = M; s = 0.f; return; }
    s = s * expf(m - M) + s2 * expf(m2 - M);
    m = M;
}

// kA: attn_logits[r] = dot(concat(embedded, h0), attn_W[r]) + attn_b[r]
// grid 512 x 256. Blocks 0..3 also zero the attn accumulator for kB.
__global__ void kA_attn_logits(const int* __restrict__ tok,
                               const float* __restrict__ hidden,
                               const float* __restrict__ emb,
                               const float* __restrict__ attn_W,
                               const float* __restrict__ attn_b,
                               float* __restrict__ ws) {
    int r = blockIdx.x, t = threadIdx.x;
    if (r < 4) ws[WS_ATTN + r * 256 + t] = 0.0f;
    size_t token = (size_t)tok[0];
    const float4* rw = (const float4*)(attn_W + (size_t)r * 2 * H);
    const float4* ev = (const float4*)(emb + token * H);
    const float4* hv = (const float4*)hidden;
    float acc = dot4(ev[t], rw[t]) + dot4(hv[t], rw[256 + t]);
    float s = wave_sum(acc);
    __shared__ float red[4];
    if ((t & 63) == 0) red[t >> 6] = s;
    __syncthreads();
    if (t == 0) ws[WS_LOGITS + r] = red[0] + red[1] + red[2] + red[3] + attn_b[r];
}

// kB: fused softmax + attn_applied. grid 128 x 256.
// Each block redundantly reduces the 512 L2-resident logits to (max,sum),
// then block (jb,lc) accumulates its 16-l chunk into attn_applied[jb*256..].
// Blocks with lc==0 also write the attn_weights output slice.
__global__ void kB_softmax_attn(const float* __restrict__ enc,
                                float* __restrict__ ws,
                                float* __restrict__ out) {
    int t = threadIdx.x, bid = blockIdx.x;
    int jb = bid >> 5, lc = bid & 31;
    float v0 = ws[WS_LOGITS + t];
    float v1 = ws[WS_LOGITS + 256 + t];
    float m = fmaxf(v0, v1);
    for (int o = 32; o > 0; o >>= 1) m = fmaxf(m, __shfl_down(m, o, 64));
    __shared__ float red[4];
    __shared__ float bm, bs;
    if ((t & 63) == 0) red[t >> 6] = m;
    __syncthreads();
    if (t == 0) bm = fmaxf(fmaxf(red[0], red[1]), fmaxf(red[2], red[3]));
    __syncthreads();
    float e = expf(v0 - bm) + expf(v1 - bm);
    float s = wave_sum(e);
    if ((t & 63) == 0) red[t >> 6] = s;
    __syncthreads();
    if (t == 0) bs = red[0] + red[1] + red[2] + red[3];
    __syncthreads();
    __shared__ float wl[16];
    int l0 = lc * 16;
    if (t < 16) wl[t] = expf(ws[WS_LOGITS + l0 + t] - bm) / bs;
    if (lc == 0 && t < 128) {
        int l = jb * 128 + t;
        out[V + 2 * H + l] = expf(ws[WS_LOGITS + l] - bm) / bs;
    }
    __syncthreads();
    int j = jb * 256 + t;
    float acc = 0.f;
#pragma unroll
    for (int i = 0; i < 16; ++i)
        acc += wl[i] * enc[(size_t)(l0 + i) * H + j];
    atomicAdd(&ws[WS_ATTN + j], acc);
}

// kC: x[i] = relu(dot(concat(embedded, attn_applied), comb_W[i]) + comb_b[i])
// grid 64 x 256 (4 waves x 4 rows each = 16 rows/block)
__global__ void kC_combine(const int* __restrict__ tok,
                           const float* __restrict__ emb,
                           const float* __restrict__ comb_W,
                           const float* __restrict__ comb_b,
                           float* __restrict__ ws) {
    int t = threadIdx.x;
    int w = t >> 6, l = t & 63;
    size_t token = (size_t)tok[0];
    __shared__ float4 vec4[512];
    vec4[t] = ((const float4*)(emb + token * H))[t];
    vec4[256 + t] = ((const float4*)(ws + WS_ATTN))[t];
    __syncthreads();
    const float4* cw = (const float4*)comb_W;
#pragma unroll
    for (int rr = 0; rr < 4; ++rr) {
        int r = blockIdx.x * 16 + w * 4 + rr;
        float acc = 0.f;
#pragma unroll
        for (int i = 0; i < 8; ++i)
            acc += dot4(cw[(size_t)r * 512 + i * 64 + l], vec4[i * 64 + l]);
        float s = wave_sum(acc);
        if (l == 0) ws[WS_X + r] = fmaxf(s + comb_b[r], 0.0f);
    }
}

// kD: fused gates + LSTM pointwise. grid 256 x 256.
// Wave w of block b owns hidden unit n=b*4+w: computes all 4 gate rows,
// then the LSTM pointwise in lane 0. Writes h (ws+out) and c (out).
__global__ void kD_gates_lstm(const float* __restrict__ hidden,
                              const float* __restrict__ W_ih,
                              const float* __restrict__ W_hh,
                              const float* __restrict__ b_ih,
                              const float* __restrict__ b_hh,
                              float* __restrict__ ws,
                              float* __restrict__ out) {
    int t = threadIdx.x;
    int w = t >> 6, l = t & 63;
    __shared__ float4 xs[256], hs[256];
    xs[t] = ((const float4*)(ws + WS_X))[t];
    hs[t] = ((const float4*)hidden)[t];
    __syncthreads();
    int n = blockIdx.x * 4 + w;
    const float4* wi = (const float4*)W_ih;
    const float4* wh = (const float4*)W_hh;
    float g[4];
#pragma unroll
    for (int gg = 0; gg < 4; ++gg) {
        int row = gg * H + n;
        float acc = 0.f;
#pragma unroll
        for (int i = 0; i < 4; ++i) {
            acc += dot4(wi[(size_t)row * 256 + i * 64 + l], xs[i * 64 + l]);
            acc += dot4(wh[(size_t)row * 256 + i * 64 + l], hs[i * 64 + l]);
        }
        float s = wave_sum(acc);
        if (l == 0) g[gg] = s + b_ih[row] + b_hh[row];
    }
    if (l == 0) {
        float c0 = hidden[n];
        float c = sigf(g[1]) * c0 + sigf(g[0]) * tanhf(g[2]);
        float h = sigf(g[3]) * tanhf(c);
        ws[WS_H + n] = h;
        out[V + n] = h;
        out[V + H + n] = c;
    }
}

// kE: vocab logits + per-block online-softmax partial. grid 1571 x 256.
__global__ void kE_vocab(const float* __restrict__ out_W,
                         const float* __restrict__ out_b,
                         float* __restrict__ ws) {
    int t = threadIdx.x;
    int w = t >> 6, l = t & 63;
    const float4* h4 = (const float4*)(ws + WS_H);
    float4 hr[4];
#pragma unroll
    for (int i = 0; i < 4; ++i) hr[i] = h4[i * 64 + l];
    const float4* ow = (const float4*)out_W;
    float pm = -INFINITY, psv = 0.f;
#pragma unroll
    for (int rr = 0; rr < 8; ++rr) {
        int r = blockIdx.x * 32 + w * 8 + rr;
        if (r < V) {
            float acc = 0.f;
#pragma unroll
            for (int i = 0; i < 4; ++i)
                acc += dot4(ow[(size_t)r * 256 + i * 64 + l], hr[i]);
            float s = wave_sum(acc);
            if (l == 0) {
                float logit = s + out_b[r];
                ws[WS_VLOG + r] = logit;
                float M = fmaxf(pm, logit);
                psv = psv * expf(pm - M) + expf(logit - M);
                pm = M;
            }
        }
    }
    __shared__ float sm[4], ss[4];
    if (l == 0) { sm[w] = pm; ss[w] = psv; }
    __syncthreads();
    if (t == 0) {
        float m = sm[0], s = ss[0];
        for (int i = 1; i < 4; ++i) osm_merge(m, s, sm[i], ss[i]);
        ws[WS_PART + 2 * blockIdx.x] = m;
        ws[WS_PART + 2 * blockIdx.x + 1] = s;
    }
}

// kF: every block redundantly reduces the 1571 partials (L2-resident 12.6KB)
// to the global LSE, then writes its 256-row output slice. grid 197 x 256.
__global__ void kF_logsoftmax(const float* __restrict__ ws,
                              float* __restrict__ out) {
    int t = threadIdx.x;
    float m = -INFINITY, s = 0.f;
    for (int i = t; i < NPART; i += 256)
        osm_merge(m, s, ws[WS_PART + 2 * i], ws[WS_PART + 2 * i + 1]);
    for (int o = 32; o > 0; o >>= 1) {
        float m2 = __shfl_down(m, o, 64);
        float s2 = __shfl_down(s, o, 64);
        osm_merge(m, s, m2, s2);
    }
    __shared__ float sm[4], ss[4];
    __shared__ float lse;
    if ((t & 63) == 0) { sm[t >> 6] = m; ss[t >> 6] = s; }
    __syncthreads();
    if (t == 0) {
        float mm = sm[0], sv = ss[0];
        for (int i = 1; i < 4; ++i) osm_merge(mm, sv, sm[i], ss[i]);
        lse = mm + logf(sv);
    }
    __syncthreads();
    int r = blockIdx.x * 256 + t;
    if (r < V) out[r] = ws[WS_VLOG + r] - lse;
}

extern "C" void kernel_launch(void* const* d_in, const int* in_sizes, int n_in,
                              void* d_out, int out_size, void* d_ws, size_t ws_size,
                              hipStream_t stream) {
    const int*   tok     = (const int*)d_in[0];
    const float* hidden  = (const float*)d_in[1];
    const float* enc     = (const float*)d_in[2];
    const float* emb     = (const float*)d_in[3];
    const float* attn_W  = (const float*)d_in[4];
    const float* attn_b  = (const float*)d_in[5];
    const float* comb_W  = (const float*)d_in[6];
    const float* comb_b  = (const float*)d_in[7];
    const float* W_ih    = (const float*)d_in[8];
    const float* W_hh    = (const float*)d_in[9];
    const float* b_ih    = (const float*)d_in[10];
    const float* b_hh    = (const float*)d_in[11];
    const float* out_W   = (const float*)d_in[12];
    const float* out_b   = (const float*)d_in[13];
    float* out = (float*)d_out;
    float* ws  = (float*)d_ws;

    kA_attn_logits<<<512, 256, 0, stream>>>(tok, hidden, emb, attn_W, attn_b, ws);
    kB_softmax_attn<<<128, 256, 0, stream>>>(enc, ws, out);
    kC_combine<<<64, 256, 0, stream>>>(tok, emb, comb_W, comb_b, ws);
    kD_gates_lstm<<<256, 256, 0, stream>>>(hidden, W_ih, W_hh, b_ih, b_hh, ws, out);
    kE_vocab<<<1571, 256, 0, stream>>>(out_W, out_b, ws);
    kF_logsoftmax<<<197, 256, 0, stream>>>(ws, out);
}